// Round 7
// baseline (94.817 us; speedup 1.0000x reference)
//
#include <hip/hip_runtime.h>
#include <hip/hip_bf16.h>

// Problem constants
#define B_N   8192
#define OBS   128
#define HID   512
#define VSZ   256
#define NU    64
#define TOPK  8
#define NOPT  16
#define KEXT  160   // 128 x-cols + 1 bias col + 31 zero pad

typedef __bf16 bf16_t;
typedef __bf16 bf16x8 __attribute__((ext_vector_type(8)));
typedef float  f32x4  __attribute__((ext_vector_type(4)));

// Workspace layout (bytes)
#define OFF_A    0u         // 16 f32
#define OFF_DP   256u       // 256 f32
#define OFF_MT   2048u      // mt[v][k] bf16 256x160 = 81920

// ---------------------------------------------------------------------------
// Kernel 1 (merged weff+mt): grid 33 x 1024.
//  blocks 0..31: own 8 v-columns of mt. Stage weff[:, v0:v0+8] in LDS straight
//    from value_w (no global weff round-trip), then mt[v][k] = sum_j pw[k][j]*
//    weff_lds[j][vi] with thread = (k, vi). c row (k=128) via 128-thread
//    partial reduce; pad cols 129..159 zeroed.
//  block 32: A[16] (waves 0..3) and Dp (tids 256..511).
__launch_bounds__(1024)
__global__ void k_wmt(const float* __restrict__ vw, const float* __restrict__ pw,
                      const float* __restrict__ pb, const float* __restrict__ p_w,
                      const float* __restrict__ p_b, const float* __restrict__ vb,
                      bf16_t* __restrict__ mt, float* __restrict__ A,
                      float* __restrict__ Dp) {
    const int tid = threadIdx.x;

    if (blockIdx.x == 32) {
        // A[opt]: waves 0..3, wave w handles options 4w..4w+3
        int wvi = tid >> 6;
        if (wvi < 4) {
            int lane = tid & 63;
            #pragma unroll
            for (int oo = 0; oo < 4; ++oo) {
                int o = wvi * 4 + oo;
                float cur = p_w[o * NU + lane] + p_b[lane];
                float sum = 0.f;
                #pragma unroll
                for (int t = 0; t < TOPK; ++t) {
                    float m = cur;
                    #pragma unroll
                    for (int off = 32; off >= 1; off >>= 1)
                        m = fmaxf(m, __shfl_xor(m, off));
                    sum += 1.f / (1.f + expf(-m));
                    unsigned long long bal = __ballot(cur == m);
                    int first = __ffsll(bal) - 1;   // lowest index: jax tie-break
                    if (lane == first) cur = -1e30f;
                }
                if (lane == 0) A[o] = sum * (1.f / NU);
            }
        }
        if (tid >= 256 && tid < 512) {
            int v = tid & 255;
            Dp[v] = 0.03125f * ((vb[v] + vb[v + VSZ]) + (vb[v + 2 * VSZ] + vb[v + 3 * VSZ]));
        }
        return;
    }

    __shared__ float wl[HID][8];      // 16 KB: weff[:, v0:v0+8]
    __shared__ float cpart[16][8];

    const int v0 = blockIdx.x * 8;

    // Stage: wl[j][vi] = 0.25 * sum_h vw[j][h*256 + v0+vi]
    #pragma unroll
    for (int r = 0; r < 4; ++r) {
        int e  = tid + r * 1024;      // 4096 entries = 512 j x 8 vi
        int j  = e >> 3, vi = e & 7;
        const float* p = vw + j * (4 * VSZ) + v0 + vi;
        wl[j][vi] = 0.25f * ((p[0] + p[VSZ]) + (p[2 * VSZ] + p[3 * VSZ]));
    }
    __syncthreads();

    // Main: thread = (k, vi); 512-j dot product, pw rows stream f32x4.
    {
        int k  = tid >> 3, vi = tid & 7;
        const float* pr = pw + k * HID;
        float a0 = 0.f, a1 = 0.f, a2 = 0.f, a3 = 0.f;
        #pragma unroll 4
        for (int j = 0; j < HID; j += 4) {
            f32x4 p = *(const f32x4*)(pr + j);
            a0 += p[0] * wl[j + 0][vi];
            a1 += p[1] * wl[j + 1][vi];
            a2 += p[2] * wl[j + 2][vi];
            a3 += p[3] * wl[j + 3][vi];
        }
        mt[(v0 + vi) * KEXT + k] = (bf16_t)((a0 + a1) + (a2 + a3));
    }

    // c row (k=128): 128 threads do 16-way j-split partials, then 8 reduce.
    if (tid < 128) {
        int jq = tid >> 3, cvi = tid & 7;
        const float* pbq = pb + jq * 32;
        float s = 0.f;
        #pragma unroll 4
        for (int j = 0; j < 32; ++j) s += pbq[j] * wl[jq * 32 + j][cvi];
        cpart[jq][cvi] = s;
    }
    __syncthreads();
    if (tid < 8) {
        float s = 0.f;
        #pragma unroll
        for (int q = 0; q < 16; ++q) s += cpart[q][tid];
        mt[(v0 + tid) * KEXT + 128] = (bf16_t)s;
    }
    // pad cols 129..159
    if (tid < 256) {
        int pvi = tid >> 5, kk = tid & 31;
        if (kk < 31) mt[(v0 + pvi) * KEXT + 129 + kk] = (bf16_t)0.f;
    }
}

// ---------------------------------------------------------------------------
// Kernel 2: out[b][v] = A[opt[b]] * (x' @ M')[b][v] + Dp[v]
// x' = [x | 1 | 0...], M' = [M ; c ; 0...]; K = 160. f32 x -> bf16 in-register.
// MFMA 16x16x32. Block = 4 waves; wave: 16 rows x 128 cols.
// grid (8192/64, 256/128) = (128, 2).
__launch_bounds__(256)
__global__ void k_main(const float* __restrict__ x, const bf16_t* __restrict__ mt,
                       const int* __restrict__ opt, const float* __restrict__ A,
                       const float* __restrict__ Dp, float* __restrict__ out) {
    const int wave = threadIdx.x >> 6;
    const int lane = threadIdx.x & 63;
    const int mrow = lane & 15;
    const int quad = lane >> 4;
    const int r0   = blockIdx.x * 64 + wave * 16;
    const int c0   = blockIdx.y * 128;

    // A-fragments first: all x loads in flight before mt reads
    bf16x8 af[5];
    {
        const float* xr = x + (r0 + mrow) * OBS + quad * 8;
        f32x4 lo[4], hi[4];
        #pragma unroll
        for (int kt = 0; kt < 4; ++kt) {
            lo[kt] = *(const f32x4*)(xr + kt * 32);
            hi[kt] = *(const f32x4*)(xr + kt * 32 + 4);
        }
        #pragma unroll
        for (int kt = 0; kt < 4; ++kt) {
            bf16x8 a;
            a[0] = (bf16_t)lo[kt][0]; a[1] = (bf16_t)lo[kt][1];
            a[2] = (bf16_t)lo[kt][2]; a[3] = (bf16_t)lo[kt][3];
            a[4] = (bf16_t)hi[kt][0]; a[5] = (bf16_t)hi[kt][1];
            a[6] = (bf16_t)hi[kt][2]; a[7] = (bf16_t)hi[kt][3];
            af[kt] = a;
        }
        bf16x8 a;
        #pragma unroll
        for (int j = 0; j < 8; ++j) a[j] = (bf16_t)0.f;
        if (quad == 0) a[0] = (bf16_t)1.0f;   // k=128: bias column
        af[4] = a;
    }

    // per-row scale gathered before the MFMA loop
    float av[4];
    #pragma unroll
    for (int r = 0; r < 4; ++r)
        av[r] = A[opt[r0 + quad * 4 + r]];

    f32x4 acc[8];
    #pragma unroll
    for (int t = 0; t < 8; ++t) acc[t] = (f32x4){0.f, 0.f, 0.f, 0.f};

    const bf16_t* mb = mt + (c0 + mrow) * KEXT + quad * 8;
    #pragma unroll
    for (int kt = 0; kt < 5; ++kt) {
        #pragma unroll
        for (int t = 0; t < 8; ++t) {
            bf16x8 b = *(const bf16x8*)(mb + t * 16 * KEXT + kt * 32);
            acc[t] = __builtin_amdgcn_mfma_f32_16x16x32_bf16(af[kt], b, acc[t], 0, 0, 0);
        }
    }

    // C/D layout: col=lane&15, row=quad*4+reg
    #pragma unroll
    for (int r = 0; r < 4; ++r) {
        int row = r0 + quad * 4 + r;
        float* orow = out + row * VSZ;
        #pragma unroll
        for (int t = 0; t < 8; ++t) {
            int col = c0 + t * 16 + mrow;
            orow[col] = av[r] * acc[t][r] + Dp[col];
        }
    }
}

// ---------------------------------------------------------------------------
extern "C" void kernel_launch(void* const* d_in, const int* in_sizes, int n_in,
                              void* d_out, int out_size, void* d_ws, size_t ws_size,
                              hipStream_t stream) {
    const float* x        = (const float*)d_in[0];
    const int*   option   = (const int*)  d_in[1];
    const float* pre_fc_w = (const float*)d_in[2];
    const float* pre_fc_b = (const float*)d_in[3];
    const float* value_w  = (const float*)d_in[4];
    const float* value_b  = (const float*)d_in[5];
    const float* p_w      = (const float*)d_in[6];
    const float* p_b      = (const float*)d_in[7];
    float* out = (float*)d_out;

    char* ws = (char*)d_ws;
    float*  A    = (float*) (ws + OFF_A);
    float*  Dp   = (float*) (ws + OFF_DP);
    bf16_t* mt   = (bf16_t*)(ws + OFF_MT);

    k_wmt <<<dim3(33), dim3(1024), 0, stream>>>(value_w, pre_fc_w, pre_fc_b,
                                                p_w, p_b, value_b, mt, A, Dp);
    k_main<<<dim3(B_N / 64, VSZ / 128), dim3(256), 0, stream>>>(x, mt, option, A, Dp, out);
}